// Round 4
// baseline (313.071 us; speedup 1.0000x reference)
//
#include <hip/hip_runtime.h>
#include <hip/hip_bf16.h>
#include <cstdint>

// Problem constants
#define CIN   256
#define COUT  256
#define NB    8
#define NT    16
#define NH    28
#define NW    28
#define HP    30
#define WP    30

#define XM_ELEMS   ((size_t)NB * NT * HP * WP * CIN)   // 29,491,200 bf16
#define XM_BYTES   (XM_ELEMS * 2)
#define SPAT_MAX   (NB * NT * HP * WP - 1)             // 115199

typedef __bf16 bf16x8 __attribute__((ext_vector_type(8)));
typedef float  f32x4  __attribute__((ext_vector_type(4)));

#define AS1 __attribute__((address_space(1)))
#define AS3 __attribute__((address_space(3)))

static __device__ __forceinline__ unsigned short f2bf(float f) {
    __hip_bfloat16 h = __float2bfloat16(f);
    return __builtin_bit_cast(unsigned short, h);
}

// ---------------------------------------------------------------------------
// Pass 1: xm[b][t][hp][wp][ci] = bf16(x[b][ci][t][h][w] * alpha[b][ci][t])
// ---------------------------------------------------------------------------
__global__ void modulate_kernel(const float* __restrict__ x,
                                const float* __restrict__ alpha,
                                unsigned short* __restrict__ xm) {
    const int ci = threadIdx.x;
    const int blk = blockIdx.x;
    const int hp = blk % 30;
    const int bt = blk / 30;
    unsigned short* row = xm + (size_t)(bt * 900 + hp * 30) * 256;
    if (hp == 0 || hp == 29) {
        #pragma unroll
        for (int wp = 0; wp < 30; ++wp) row[wp * 256 + ci] = 0;
        return;
    }
    const int t = bt & 15, b = bt >> 4;
    const int h = hp - 1;
    const float a = alpha[(b * CIN + ci) * NT + t];
    const float* xrow = x + ((size_t)((b * CIN + ci) * NT + t) * NH + h) * NW;
    row[ci] = 0;
    row[29 * 256 + ci] = 0;
    const float4* xv = (const float4*)xrow;
    #pragma unroll
    for (int q = 0; q < 7; ++q) {
        float4 v = xv[q];
        row[(q * 4 + 1) * 256 + ci] = f2bf(v.x * a);
        row[(q * 4 + 2) * 256 + ci] = f2bf(v.y * a);
        row[(q * 4 + 3) * 256 + ci] = f2bf(v.z * a);
        row[(q * 4 + 4) * 256 + ci] = f2bf(v.w * a);
    }
}

// ---------------------------------------------------------------------------
// Pass 2: wB[tap][co][ci] = bf16(weight[co][ci][tap])
// ---------------------------------------------------------------------------
__global__ void repack_w_kernel(const float* __restrict__ w,
                                unsigned short* __restrict__ wB) {
    const int ci = threadIdx.x;
    const int tap = blockIdx.x >> 8;
    const int co  = blockIdx.x & 255;
    wB[((tap * 256 + co) * 256) + ci] = f2bf(w[(co * 256 + ci) * 9 + tap]);
}

// ---------------------------------------------------------------------------
// Pass 3: 256(co) x 224(n) implicit GEMM with tap-halo reuse.
// K order: 4 ci-blocks (outer) x 9 taps (inner), BK=64.
// Per ci-block: stage the tile's 12-row padded spatial halo (360 x 128B,
// contiguous in xm) ONCE; the 9 taps read it at constant row offsets.
// A (weights) double-buffered per kt. One barrier + one counted VMW per kt,
// 56 MFMA per wave per kt. LDS = 2x32KB (A) + 2x45KB (halo) = 157.7KB.
// grid = 448, block = 512 (8 waves: 4M x 2N).
// ---------------------------------------------------------------------------

// A region: bufA(buf) elems = buf*16384; 256 rows(co) x 64(ci) elems.
#define STAGE_A(abuf, offE) do {                                              \
    _Pragma("unroll") for (int c_ = 0; c_ < 4; ++c_)                          \
        __builtin_amdgcn_global_load_lds(                                     \
            (const AS1 void*)(aSrc + (offE) + c_ * 16384),                    \
            (AS3 void*)(lds + (abuf)*16384 + c_*4096 + wave*512 + lane*8),    \
            16, 0, 0);                                                        \
} while (0)

// Halo region: base elem 32768 + hbuf*23040; 360 rows x 64 elems.
// 6 calls/wave (uniform vmcnt): c=0..4 cover rows 0..319, c=5 covers
// 320..359 (waves 0-4) and duplicates rows 0..23 (waves 5-7, benign).
#define STAGE_HALO(hbuf, ci0) do {                                            \
    _Pragma("unroll") for (int c_ = 0; c_ < 5; ++c_) {                        \
        int row_ = c_*64 + wave*8 + (lane>>3);                                \
        int spat_ = haloSpat0 + row_;                                         \
        spat_ = spat_ > SPAT_MAX ? SPAT_MAX : spat_;                          \
        __builtin_amdgcn_global_load_lds(                                     \
            (const AS1 void*)(xm + (size_t)spat_*256 + (ci0) + swz8),         \
            (AS3 void*)(lds + 32768 + (hbuf)*23040 + (c_*64 + wave*8)*64 + lane*8), \
            16, 0, 0);                                                        \
    }                                                                         \
    {   int rg_ = (wave < 5) ? (320 + wave*8) : ((wave - 5)*8);               \
        int row_ = rg_ + (lane>>3);                                           \
        int spat_ = haloSpat0 + row_;                                         \
        spat_ = spat_ > SPAT_MAX ? SPAT_MAX : spat_;                          \
        __builtin_amdgcn_global_load_lds(                                     \
            (const AS1 void*)(xm + (size_t)spat_*256 + (ci0) + swz8),         \
            (AS3 void*)(lds + 32768 + (hbuf)*23040 + rg_*64 + lane*8),        \
            16, 0, 0); }                                                      \
} while (0)

#define READ_FA(abuf) do {                                                    \
    _Pragma("unroll") for (int m_ = 0; m_ < 4; ++m_)                          \
    _Pragma("unroll") for (int kk_ = 0; kk_ < 2; ++kk_)                       \
        fa[m_][kk_] = *(const bf16x8*)(lds + (abuf)*16384 +                   \
            (wm*64 + m_*16 + l15)*64 + (kslot ^ (kk_*32)));                   \
} while (0)

// fb[slot] <- halo frag for n-frag f at tap offset TO (elems, 128B rows)
#define READ_FB1(slot, hbuf, f_, TO) do {                                     \
    const int row_ = localB[f_] + (TO);                                       \
    const int sw_  = ((lane>>4)*8) ^ ((row_ & 7)*8);                          \
    _Pragma("unroll") for (int kk_ = 0; kk_ < 2; ++kk_)                       \
        fb[slot][kk_] = *(const bf16x8*)(lds + 32768 + (hbuf)*23040 +         \
            row_*64 + (sw_ ^ (kk_*32)));                                      \
} while (0)

// swapped operands: D rows = n (fb free-dim), cols = co (fa free-dim)
#define MFMA_A() do {                                                         \
    _Pragma("unroll") for (int m_ = 0; m_ < 4; ++m_)                          \
    _Pragma("unroll") for (int f_ = 0; f_ < 4; ++f_)                          \
    _Pragma("unroll") for (int kk_ = 0; kk_ < 2; ++kk_)                       \
        acc[m_][f_] = __builtin_amdgcn_mfma_f32_16x16x32_bf16(                \
            fb[f_][kk_], fa[m_][kk_], acc[m_][f_], 0, 0, 0);                  \
} while (0)

#define MFMA_B() do {                                                         \
    _Pragma("unroll") for (int m_ = 0; m_ < 4; ++m_)                          \
    _Pragma("unroll") for (int f_ = 0; f_ < 3; ++f_)                          \
    _Pragma("unroll") for (int kk_ = 0; kk_ < 2; ++kk_)                       \
        acc[m_][4+f_] = __builtin_amdgcn_mfma_f32_16x16x32_bf16(              \
            fb[f_][kk_], fa[m_][kk_], acc[m_][4+f_], 0, 0, 0);                \
} while (0)

#define BAR()   __builtin_amdgcn_s_barrier()
#define VMW(N)  asm volatile("s_waitcnt vmcnt(" #N ")" ::: "memory")
#define PRIO(x) __builtin_amdgcn_s_setprio(x)

__global__ __launch_bounds__(512, 2) void conv_gemm_kernel(
    const unsigned short* __restrict__ xm,
    const unsigned short* __restrict__ wB,
    float* __restrict__ out) {
    __shared__ unsigned short lds[78848];   // 157,696 B

    const int tid  = threadIdx.x;
    const int wave = tid >> 6;
    const int lane = tid & 63;
    const int n0   = blockIdx.x * 224;
    const int wm   = wave >> 1;            // 0..3 M-quarter (64 co)
    const int wn   = wave & 1;             // 0..1 N-half (112 n)
    const int l15  = lane & 15;
    const int kslot = ((lane >> 4) * 8) ^ ((l15 & 7) * 8);   // A frag swizzle

    // ---- halo geometry (n0 % 28 == 0 always) ----
    const int r0 = blockIdx.x * 8;                 // n0 / 28
    const int prow_start = r0 + 2 * (r0 / 28);
    const int haloSpat0  = prow_start * 30;

    // per-lane local center rows (128B-row units in halo) for n-frags 0..6
    int localB[7];
    #pragma unroll
    for (int f = 0; f < 7; ++f) {
        const int m = wn * 112 + f * 16 + l15;     // 0..223
        const int r = r0 + m / 28;
        const int w_ = m % 28;
        const int prow_c = r + 2 * (r / 28) + 1;
        localB[f] = (prow_c - prow_start) * 30 + (w_ + 1);
    }

    // ---- staging sources (pre-swizzled ci offset) ----
    const int swz8 = 8 * ((lane & 7) ^ ((lane >> 3) & 7));
    const unsigned short* aSrc = wB + (wave * 8 + (lane >> 3)) * 256 + swz8;

    f32x4 acc[4][7];
    #pragma unroll
    for (int i = 0; i < 4; ++i)
        #pragma unroll
        for (int j = 0; j < 7; ++j) acc[i][j] = f32x4{0.f,0.f,0.f,0.f};

    bf16x8 fa[4][2], fb[4][2];

    // tap row offsets: (kh-1)*30 + (kw-1)
    // taps: 0..8 -> {-31,-30,-29,-1,0,1,29,30,31}

    // ---- prologue: A(kt0) -> bufA0, halo(cb0) -> bufH0 ----
    STAGE_A(0, 0);
    STAGE_HALO(0, 0);
    VMW(0);
    BAR();

    #pragma unroll 1
    for (int cb = 0; cb < 4; ++cb) {
        const int hb = cb & 1;
        #pragma unroll
        for (int tap = 0; tap < 9; ++tap) {
            const int kt = cb * 9 + tap;
            const int ab = kt & 1;
            const int TO = ((tap / 3) - 1) * 30 + ((tap % 3) - 1);

            // fragment reads (current buffers)
            READ_FA(ab);
            READ_FB1(0, hb, 0, TO);
            READ_FB1(1, hb, 1, TO);
            READ_FB1(2, hb, 2, TO);
            READ_FB1(3, hb, 3, TO);

            // stage next A-tile
            if (!(cb == 3 && tap == 8)) {
                const int tapN = (tap == 8) ? 0 : tap + 1;
                const int cbN  = (tap == 8) ? cb + 1 : cb;
                STAGE_A(ab ^ 1, tapN * 65536 + cbN * 64);
            }
            // stage next ci-block's halo at tap 6
            if (tap == 6 && cb < 3) STAGE_HALO(hb ^ 1, (cb + 1) * 64);

            PRIO(1);
            MFMA_A();
            READ_FB1(0, hb, 4, TO);
            READ_FB1(1, hb, 5, TO);
            READ_FB1(2, hb, 6, TO);
            MFMA_B();
            PRIO(0);

            if (tap == 6 && cb < 3) { VMW(6); }   // drain A(kt+1), keep halo
            else                    { VMW(0); }   // drain everything issued
            BAR();
        }
    }

    // ---- C-write: lane holds 4 consecutive n (rows) at one co (col) ----
    #pragma unroll
    for (int f = 0; f < 7; ++f) {
        const int n  = n0 + wn * 112 + f * 16 + ((lane >> 4) << 2);
        const int bt = n / 784;
        const int hw = n - bt * 784;
        const int b = bt >> 4, t = bt & 15;
        float* obase = out + ((size_t)(b * 256) * 16 + t) * 784 + hw;
        #pragma unroll
        for (int m = 0; m < 4; ++m) {
            const int co = wm * 64 + m * 16 + l15;
            *(f32x4*)(obase + (size_t)co * 12544) = acc[m][f];
        }
    }
}

// ---------------------------------------------------------------------------
extern "C" void kernel_launch(void* const* d_in, const int* in_sizes, int n_in,
                              void* d_out, int out_size, void* d_ws, size_t ws_size,
                              hipStream_t stream) {
    const float* x      = (const float*)d_in[0];
    const float* alpha  = (const float*)d_in[1];
    const float* weight = (const float*)d_in[2];
    float* out = (float*)d_out;

    unsigned short* xm = (unsigned short*)d_ws;
    unsigned short* wB = (unsigned short*)((char*)d_ws + XM_BYTES);

    modulate_kernel<<<dim3(NB * NT * HP), dim3(256), 0, stream>>>(x, alpha, xm);
    repack_w_kernel<<<dim3(9 * 256), dim3(256), 0, stream>>>(weight, wB);
    conv_gemm_kernel<<<dim3(448), dim3(512), 0, stream>>>(xm, wB, out);
}

// Round 5
// 220.389 us; speedup vs baseline: 1.4205x; 1.4205x over previous
//
#include <hip/hip_runtime.h>
#include <hip/hip_bf16.h>
#include <cstdint>

// Problem constants
#define CIN   256
#define COUT  256
#define NB    8
#define NT    16
#define NH    28
#define NW    28
#define HP    30
#define WP    30

#define XM_ELEMS   ((size_t)NB * NT * HP * WP * CIN)   // 29,491,200 bf16
#define XM_BYTES   (XM_ELEMS * 2)

typedef __bf16 bf16x8 __attribute__((ext_vector_type(8)));
typedef float  f32x4  __attribute__((ext_vector_type(4)));

#define AS1 __attribute__((address_space(1)))
#define AS3 __attribute__((address_space(3)))

static __device__ __forceinline__ unsigned short f2bf(float f) {
    __hip_bfloat16 h = __float2bfloat16(f);
    return __builtin_bit_cast(unsigned short, h);
}

// ---------------------------------------------------------------------------
// Pass 1: xm[b][t][hp][wp][ci] = bf16(x[b][ci][t][h][w] * alpha[b][ci][t])
// ---------------------------------------------------------------------------
__global__ void modulate_kernel(const float* __restrict__ x,
                                const float* __restrict__ alpha,
                                unsigned short* __restrict__ xm) {
    const int ci = threadIdx.x;
    const int blk = blockIdx.x;
    const int hp = blk % 30;
    const int bt = blk / 30;
    unsigned short* row = xm + (size_t)(bt * 900 + hp * 30) * 256;
    if (hp == 0 || hp == 29) {
        #pragma unroll
        for (int wp = 0; wp < 30; ++wp) row[wp * 256 + ci] = 0;
        return;
    }
    const int t = bt & 15, b = bt >> 4;
    const int h = hp - 1;
    const float a = alpha[(b * CIN + ci) * NT + t];
    const float* xrow = x + ((size_t)((b * CIN + ci) * NT + t) * NH + h) * NW;
    row[ci] = 0;
    row[29 * 256 + ci] = 0;
    const float4* xv = (const float4*)xrow;
    #pragma unroll
    for (int q = 0; q < 7; ++q) {
        float4 v = xv[q];
        row[(q * 4 + 1) * 256 + ci] = f2bf(v.x * a);
        row[(q * 4 + 2) * 256 + ci] = f2bf(v.y * a);
        row[(q * 4 + 3) * 256 + ci] = f2bf(v.z * a);
        row[(q * 4 + 4) * 256 + ci] = f2bf(v.w * a);
    }
}

// ---------------------------------------------------------------------------
// Pass 2: wB[tap][co][ci] = bf16(weight[co][ci][tap])
// ---------------------------------------------------------------------------
__global__ void repack_w_kernel(const float* __restrict__ w,
                                unsigned short* __restrict__ wB) {
    const int ci = threadIdx.x;
    const int tap = blockIdx.x >> 8;
    const int co  = blockIdx.x & 255;
    wB[((tap * 256 + co) * 256) + ci] = f2bf(w[(co * 256 + ci) * 9 + tap]);
}

// ---------------------------------------------------------------------------
// Pass 3: 128(co) x 112(n) implicit GEMM, BK=32, K=2304 = 72 kt.
// grid = 1792 (= 7 blocks/CU exactly), block = 128 (2 waves), 32KB LDS
// -> 4 blocks/CU co-resident: independent blocks overlap LDS pipe vs MFMA.
// Per kt: VMW(8); BAR; 11 ds_read_b128; LGKM0; BAR; stage(kt+2, 8 loads);
// 28 MFMA. Double-buffered A/B (parity kt&1). 64B LDS rows, swizzle
// col ^= (row>>1)&3 (0-conflict), pre-swizzled global_load_lds source.
// ---------------------------------------------------------------------------

#define BAR()    __builtin_amdgcn_s_barrier()
#define LGKM0()  asm volatile("s_waitcnt lgkmcnt(0)" ::: "memory")
#define VMW(N)   asm volatile("s_waitcnt vmcnt(" #N ")" ::: "memory")
#define SCHED0() __builtin_amdgcn_sched_barrier(0)
#define PRIO(x)  __builtin_amdgcn_s_setprio(x)

// stage kt' into parity-P buffers; aOffE/bOffE are element offsets
#define STAGE(P, aOffE, bOffE) do {                                           \
    _Pragma("unroll") for (int a_ = 0; a_ < 4; ++a_)                          \
        __builtin_amdgcn_global_load_lds(                                     \
            (const AS1 void*)(aSrcLane + (aOffE) + a_ * 4096),                \
            (AS3 void*)(lds + (P)*8192 + wv*4096 + a_*1024 + lane*16),        \
            16, 0, 0);                                                        \
    _Pragma("unroll") for (int b_ = 0; b_ < 4; ++b_)                          \
        __builtin_amdgcn_global_load_lds(                                     \
            (const AS1 void*)(bL[b_] + (bOffE)),                              \
            (AS3 void*)(lds + 16384 + (P)*8192 + wv*4096 + b_*1024 + lane*16),\
            16, 0, 0);                                                        \
} while (0)

#define READF(P) do {                                                         \
    _Pragma("unroll") for (int m_ = 0; m_ < 4; ++m_)                          \
        fa[m_] = *(const bf16x8*)(lds + (P)*8192 + aRdBase + m_*1024);        \
    _Pragma("unroll") for (int f_ = 0; f_ < 7; ++f_)                          \
        fb[f_] = *(const bf16x8*)(lds + 16384 + (P)*8192 + bRdBase + f_*1024);\
} while (0)

#define MFMA28() do {                                                         \
    _Pragma("unroll") for (int m_ = 0; m_ < 4; ++m_)                          \
    _Pragma("unroll") for (int f_ = 0; f_ < 7; ++f_)                          \
        acc[m_][f_] = __builtin_amdgcn_mfma_f32_16x16x32_bf16(                \
            fb[f_], fa[m_], acc[m_][f_], 0, 0, 0);                            \
} while (0)

__global__ __launch_bounds__(128, 2) void conv_gemm_kernel(
    const unsigned short* __restrict__ xm,
    const unsigned short* __restrict__ wB,
    float* __restrict__ out) {
    __shared__ __align__(1024) char lds[32768];

    const int tid  = threadIdx.x;
    const int wv   = tid >> 6;             // 0..1: co sub-tile
    const int lane = tid & 63;
    const int l15  = lane & 15;
    const int bx   = blockIdx.x;
    const int co0  = (bx & 1) << 7;        // 0 or 128
    const int n0   = (bx >> 1) * 112;

    // ---- staging sources (pre-swizzled ci offset; inverse of read swizzle) ----
    const int swzE = 8 * ((lane & 3) ^ ((lane >> 3) & 3));
    const unsigned short* aSrcLane =
        wB + (co0 + wv * 64 + (lane >> 2)) * 256 + swzE;

    const unsigned short* bL[4];
    #pragma unroll
    for (int b_ = 0; b_ < 4; ++b_) {
        int nl = wv * 64 + b_ * 16 + (lane >> 2);
        nl = nl > 111 ? 111 : nl;          // pad rows duplicate row 111
        const int n  = n0 + nl;
        const int w_ = n % 28, h_ = (n / 28) % 28, bt = n / 784;
        bL[b_] = xm + (size_t)((bt * 30 + h_ + 1) * 30 + (w_ + 1)) * 256 + swzE;
    }

    // ---- fragment read bases (byte offsets; swizzle col ^= (row>>1)&3) ----
    const int readSwz = ((lane >> 4) ^ ((l15 >> 1) & 3)) << 4;
    const int aRdBase = wv * 4096 + l15 * 64 + readSwz;   // + P*8192 + m*1024
    const int bRdBase = l15 * 64 + readSwz;               // +16384 + P*8192 + f*1024

    f32x4 acc[4][7];
    #pragma unroll
    for (int i = 0; i < 4; ++i)
        #pragma unroll
        for (int j = 0; j < 7; ++j) acc[i][j] = f32x4{0.f, 0.f, 0.f, 0.f};

    bf16x8 fa[4], fb[7];

    // ---- prologue: stage kt=0 -> buf0, kt=1 -> buf1 (tap 0, cic 0/1) ----
    STAGE(0, 0, (-31) * 256);
    STAGE(1, 32, (-31) * 256 + 32);

    #pragma unroll 1
    for (int kt = 0; kt < 71; ++kt) {
        const int p = kt & 1;
        VMW(8);            // drain S(kt); keep S(kt+1) in flight
        SCHED0();
        BAR();             // all waves' S(kt) landed
        READF(p);
        LGKM0();           // frags in regs (and reads complete for stage hazard)
        SCHED0();
        BAR();             // both waves done reading buf[p] -> safe to restage
        if (kt < 70) {     // stage kt+2 into buf[p]
            const int k2 = kt + 2;
            const int tap2 = k2 >> 3, cic2 = k2 & 7;
            const int kh2 = (tap2 * 11) >> 5;
            const int kw2 = tap2 - 3 * kh2;
            STAGE(p, tap2 * 65536 + cic2 * 32,
                     ((kh2 - 1) * 30 + (kw2 - 1)) * 256 + cic2 * 32);
        }
        PRIO(1); MFMA28(); PRIO(0);
    }
    // ---- peeled kt=71 (buf1): full drain ----
    VMW(0);
    SCHED0();
    BAR();
    READF(1);
    LGKM0();
    SCHED0();
    PRIO(1); MFMA28(); PRIO(0);

    // ---- C-write: lane holds 4 consecutive n (rows) at one co (col) ----
    #pragma unroll
    for (int f = 0; f < 7; ++f) {
        const int n  = n0 + f * 16 + ((lane >> 4) << 2);
        const int bt = n / 784;
        const int hw = n - bt * 784;
        const int b = bt >> 4, t = bt & 15;
        float* obase = out + ((size_t)(b * 256) * 16 + t) * 784 + hw;
        #pragma unroll
        for (int m = 0; m < 4; ++m) {
            const int co = co0 + wv * 64 + m * 16 + l15;
            *(f32x4*)(obase + (size_t)co * 12544) = acc[m][f];
        }
    }
}

// ---------------------------------------------------------------------------
extern "C" void kernel_launch(void* const* d_in, const int* in_sizes, int n_in,
                              void* d_out, int out_size, void* d_ws, size_t ws_size,
                              hipStream_t stream) {
    const float* x      = (const float*)d_in[0];
    const float* alpha  = (const float*)d_in[1];
    const float* weight = (const float*)d_in[2];
    float* out = (float*)d_out;

    unsigned short* xm = (unsigned short*)d_ws;
    unsigned short* wB = (unsigned short*)((char*)d_ws + XM_BYTES);

    modulate_kernel<<<dim3(NB * NT * HP), dim3(256), 0, stream>>>(x, alpha, xm);
    repack_w_kernel<<<dim3(9 * 256), dim3(256), 0, stream>>>(weight, wB);
    conv_gemm_kernel<<<dim3(1792), dim3(128), 0, stream>>>(xm, wB, out);
}

// Round 6
// 175.937 us; speedup vs baseline: 1.7794x; 1.2527x over previous
//
#include <hip/hip_runtime.h>
#include <hip/hip_bf16.h>
#include <cstdint>

// Problem constants
#define CIN   256
#define COUT  256
#define NB    8
#define NT    16
#define NH    28
#define NW    28
#define HP    30
#define WP    30

#define XM_ELEMS   ((size_t)NB * NT * HP * WP * CIN)   // 29,491,200 bf16
#define XM_BYTES   (XM_ELEMS * 2)

typedef __bf16 bf16x8 __attribute__((ext_vector_type(8)));
typedef float  f32x4  __attribute__((ext_vector_type(4)));

#define AS1 __attribute__((address_space(1)))
#define AS3 __attribute__((address_space(3)))

static __device__ __forceinline__ unsigned short f2bf(float f) {
    __hip_bfloat16 h = __float2bfloat16(f);
    return __builtin_bit_cast(unsigned short, h);
}

// ---------------------------------------------------------------------------
// Pass 1: xm[b][t][hp][wp][ci] = bf16(x[b][ci][t][h][w] * alpha[b][ci][t])
// ---------------------------------------------------------------------------
__global__ void modulate_kernel(const float* __restrict__ x,
                                const float* __restrict__ alpha,
                                unsigned short* __restrict__ xm) {
    const int ci = threadIdx.x;
    const int blk = blockIdx.x;
    const int hp = blk % 30;
    const int bt = blk / 30;
    unsigned short* row = xm + (size_t)(bt * 900 + hp * 30) * 256;
    if (hp == 0 || hp == 29) {
        #pragma unroll
        for (int wp = 0; wp < 30; ++wp) row[wp * 256 + ci] = 0;
        return;
    }
    const int t = bt & 15, b = bt >> 4;
    const int h = hp - 1;
    const float a = alpha[(b * CIN + ci) * NT + t];
    const float* xrow = x + ((size_t)((b * CIN + ci) * NT + t) * NH + h) * NW;
    row[ci] = 0;
    row[29 * 256 + ci] = 0;
    const float4* xv = (const float4*)xrow;
    #pragma unroll
    for (int q = 0; q < 7; ++q) {
        float4 v = xv[q];
        row[(q * 4 + 1) * 256 + ci] = f2bf(v.x * a);
        row[(q * 4 + 2) * 256 + ci] = f2bf(v.y * a);
        row[(q * 4 + 3) * 256 + ci] = f2bf(v.z * a);
        row[(q * 4 + 4) * 256 + ci] = f2bf(v.w * a);
    }
}

// ---------------------------------------------------------------------------
// Pass 2: wB[tap][co][ci] = bf16(weight[co][ci][tap])
// ---------------------------------------------------------------------------
__global__ void repack_w_kernel(const float* __restrict__ w,
                                unsigned short* __restrict__ wB) {
    const int ci = threadIdx.x;
    const int tap = blockIdx.x >> 8;
    const int co  = blockIdx.x & 255;
    wB[((tap * 256 + co) * 256) + ci] = f2bf(w[(co * 256 + ci) * 9 + tap]);
}

// ---------------------------------------------------------------------------
// Pass 3: 256(co) x 112(n) implicit GEMM, BK=32, K=2304 = 72 kt, TAP-INNER
// order (kt = cic*9 + tap): the 9 taps re-read the same L2-hot window slice.
// grid = 896 (no co-split -> min HBM traffic), block = 256 (4 waves, each
// 64co x 112n, acc 4x7). Regs ~204 -> 2 waves/SIMD -> 2 blocks/CU
// co-resident: cross-block overlap hides per-kt barrier/latency chain.
// LDS 48KB: A dbuf 2x16KB + B dbuf 2x8KB, 64B rows, swizzle
// col ^= (row>>1)&3 (2-way max), pre-swizzled global_load_lds source.
// Per kt: VMW(6); BAR; 11 ds_read_b128; LGKM0; BAR; STAGE(kt+2, 6 loads);
// 28 MFMA. Double-buffered parity kt&1.
// ---------------------------------------------------------------------------

#define BAR()    __builtin_amdgcn_s_barrier()
#define LGKM0()  asm volatile("s_waitcnt lgkmcnt(0)" ::: "memory")
#define VMW(N)   asm volatile("s_waitcnt vmcnt(" #N ")" ::: "memory")
#define SCHED0() __builtin_amdgcn_sched_barrier(0)
#define PRIO(x)  __builtin_amdgcn_s_setprio(x)

// stage kt' (parity P): A 256x32 (4 chunks/wave... 4 waves x 4), B 128x32
// (4 waves x 2), aOffE/bOffE element offsets
#define STAGE(P, aOffE, bOffE) do {                                           \
    _Pragma("unroll") for (int a_ = 0; a_ < 4; ++a_)                          \
        __builtin_amdgcn_global_load_lds(                                     \
            (const AS1 void*)(aSrcLane + (aOffE) + a_ * 4096),                \
            (AS3 void*)(lds + (P)*16384 + (wv*4 + a_)*1024 + lane*16),        \
            16, 0, 0);                                                        \
    _Pragma("unroll") for (int b_ = 0; b_ < 2; ++b_)                          \
        __builtin_amdgcn_global_load_lds(                                     \
            (const AS1 void*)(bL[b_] + (bOffE)),                              \
            (AS3 void*)(lds + 32768 + (P)*8192 + (wv*2 + b_)*1024 + lane*16), \
            16, 0, 0);                                                        \
} while (0)

#define READF(P) do {                                                         \
    _Pragma("unroll") for (int m_ = 0; m_ < 4; ++m_)                          \
        fa[m_] = *(const bf16x8*)(lds + (P)*16384 + aRdBase + m_*1024);       \
    _Pragma("unroll") for (int f_ = 0; f_ < 7; ++f_)                          \
        fb[f_] = *(const bf16x8*)(lds + 32768 + (P)*8192 + bRdBase + f_*1024);\
} while (0)

#define MFMA28() do {                                                         \
    _Pragma("unroll") for (int m_ = 0; m_ < 4; ++m_)                          \
    _Pragma("unroll") for (int f_ = 0; f_ < 7; ++f_)                          \
        acc[m_][f_] = __builtin_amdgcn_mfma_f32_16x16x32_bf16(                \
            fb[f_], fa[m_], acc[m_][f_], 0, 0, 0);                            \
} while (0)

__global__ __launch_bounds__(256, 2) void conv_gemm_kernel(
    const unsigned short* __restrict__ xm,
    const unsigned short* __restrict__ wB,
    float* __restrict__ out) {
    __shared__ __align__(1024) char lds[49152];

    const int tid  = threadIdx.x;
    const int wv   = tid >> 6;             // 0..3: co quarter
    const int lane = tid & 63;
    const int l15  = lane & 15;
    const int n0   = blockIdx.x * 112;

    // ---- staging sources (pre-swizzled ci offset; inverse of read swizzle) ----
    const int swzE = 8 * ((lane & 3) ^ ((lane >> 3) & 3));
    const unsigned short* aSrcLane = wB + (wv * 64 + (lane >> 2)) * 256 + swzE;

    const unsigned short* bL[2];
    #pragma unroll
    for (int b_ = 0; b_ < 2; ++b_) {
        int nl = wv * 32 + b_ * 16 + (lane >> 2);
        nl = nl > 111 ? 111 : nl;          // pad rows duplicate row 111
        const int n  = n0 + nl;
        const int w_ = n % 28, h_ = (n / 28) % 28, bt = n / 784;
        bL[b_] = xm + (size_t)((bt * 30 + h_ + 1) * 30 + (w_ + 1)) * 256 + swzE;
    }

    // ---- fragment read bases (byte offsets; swizzle col ^= (row>>1)&3) ----
    const int readSwz = ((lane >> 4) ^ ((l15 >> 1) & 3)) << 4;
    const int aRdBase = wv * 4096 + l15 * 64 + readSwz;   // + P*16384 + m*1024
    const int bRdBase = l15 * 64 + readSwz;               // + 32768 + P*8192 + f*1024

    f32x4 acc[4][7];
    #pragma unroll
    for (int i = 0; i < 4; ++i)
        #pragma unroll
        for (int j = 0; j < 7; ++j) acc[i][j] = f32x4{0.f, 0.f, 0.f, 0.f};

    bf16x8 fa[4], fb[7];

    // ---- prologue: kt=0 (tap0,cic0) -> buf0, kt=1 (tap1,cic0) -> buf1 ----
    STAGE(0, 0, (-31) * 256);
    STAGE(1, 65536, (-30) * 256);

    int tap2 = 2, cic2 = 0;                // stage target kt+2 = cic2*9 + tap2
    #pragma unroll 1
    for (int kt = 0; kt < 71; ++kt) {
        const int p = kt & 1;
        VMW(6);            // drain S(kt); keep S(kt+1)'s 6 in flight
        SCHED0();
        BAR();             // all waves' S(kt) landed
        READF(p);
        LGKM0();           // my frags in regs
        SCHED0();
        BAR();             // all waves done reading buf[p] -> safe to restage
        if (kt < 70) {
            const int kh2 = (tap2 * 11) >> 5;
            const int kw2 = tap2 - 3 * kh2;
            STAGE(p, tap2 * 65536 + cic2 * 32,
                     ((kh2 - 1) * 30 + (kw2 - 1)) * 256 + cic2 * 32);
            if (++tap2 == 9) { tap2 = 0; ++cic2; }
        }
        PRIO(1); MFMA28(); PRIO(0);
    }
    // ---- peeled kt=71 (buf1): full drain ----
    VMW(0);
    SCHED0();
    BAR();
    READF(1);
    LGKM0();
    SCHED0();
    PRIO(1); MFMA28(); PRIO(0);

    // ---- C-write: lane holds 4 consecutive n (rows) at one co (col) ----
    #pragma unroll
    for (int f = 0; f < 7; ++f) {
        const int n  = n0 + f * 16 + ((lane >> 4) << 2);
        const int bt = n / 784;
        const int hw = n - bt * 784;
        const int b = bt >> 4, t = bt & 15;
        float* obase = out + ((size_t)(b * 256) * 16 + t) * 784 + hw;
        #pragma unroll
        for (int m = 0; m < 4; ++m) {
            const int co = wv * 64 + m * 16 + l15;
            *(f32x4*)(obase + (size_t)co * 12544) = acc[m][f];
        }
    }
}

// ---------------------------------------------------------------------------
extern "C" void kernel_launch(void* const* d_in, const int* in_sizes, int n_in,
                              void* d_out, int out_size, void* d_ws, size_t ws_size,
                              hipStream_t stream) {
    const float* x      = (const float*)d_in[0];
    const float* alpha  = (const float*)d_in[1];
    const float* weight = (const float*)d_in[2];
    float* out = (float*)d_out;

    unsigned short* xm = (unsigned short*)d_ws;
    unsigned short* wB = (unsigned short*)((char*)d_ws + XM_BYTES);

    modulate_kernel<<<dim3(NB * NT * HP), dim3(256), 0, stream>>>(x, alpha, xm);
    repack_w_kernel<<<dim3(9 * 256), dim3(256), 0, stream>>>(weight, wB);
    conv_gemm_kernel<<<dim3(896), dim3(256), 0, stream>>>(xm, wB, out);
}

// Round 7
// 173.367 us; speedup vs baseline: 1.8058x; 1.0148x over previous
//
#include <hip/hip_runtime.h>
#include <hip/hip_bf16.h>
#include <cstdint>

// Problem constants
#define CIN   256
#define COUT  256
#define NB    8
#define NT    16
#define NH    28
#define NW    28
#define HP    30
#define WP    30

#define XM_ELEMS   ((size_t)NB * NT * HP * WP * CIN)   // 29,491,200 bf16
#define XM_BYTES   (XM_ELEMS * 2)

typedef __bf16 bf16x8 __attribute__((ext_vector_type(8)));
typedef float  f32x4  __attribute__((ext_vector_type(4)));

#define AS1 __attribute__((address_space(1)))
#define AS3 __attribute__((address_space(3)))

static __device__ __forceinline__ unsigned short f2bf(float f) {
    __hip_bfloat16 h = __float2bfloat16(f);
    return __builtin_bit_cast(unsigned short, h);
}

// ---------------------------------------------------------------------------
// Pass 1: xm[b][t][hp][wp][ci] = bf16(x[b][ci][t][h][w] * alpha[b][ci][t])
// ---------------------------------------------------------------------------
__global__ void modulate_kernel(const float* __restrict__ x,
                                const float* __restrict__ alpha,
                                unsigned short* __restrict__ xm) {
    const int ci = threadIdx.x;
    const int blk = blockIdx.x;
    const int hp = blk % 30;
    const int bt = blk / 30;
    unsigned short* row = xm + (size_t)(bt * 900 + hp * 30) * 256;
    if (hp == 0 || hp == 29) {
        #pragma unroll
        for (int wp = 0; wp < 30; ++wp) row[wp * 256 + ci] = 0;
        return;
    }
    const int t = bt & 15, b = bt >> 4;
    const int h = hp - 1;
    const float a = alpha[(b * CIN + ci) * NT + t];
    const float* xrow = x + ((size_t)((b * CIN + ci) * NT + t) * NH + h) * NW;
    row[ci] = 0;
    row[29 * 256 + ci] = 0;
    const float4* xv = (const float4*)xrow;
    #pragma unroll
    for (int q = 0; q < 7; ++q) {
        float4 v = xv[q];
        row[(q * 4 + 1) * 256 + ci] = f2bf(v.x * a);
        row[(q * 4 + 2) * 256 + ci] = f2bf(v.y * a);
        row[(q * 4 + 3) * 256 + ci] = f2bf(v.z * a);
        row[(q * 4 + 4) * 256 + ci] = f2bf(v.w * a);
    }
}

// ---------------------------------------------------------------------------
// Pass 2: wB[tap][co][ci] = bf16(weight[co][ci][tap])
// ---------------------------------------------------------------------------
__global__ void repack_w_kernel(const float* __restrict__ w,
                                unsigned short* __restrict__ wB) {
    const int ci = threadIdx.x;
    const int tap = blockIdx.x >> 8;
    const int co  = blockIdx.x & 255;
    wB[((tap * 256 + co) * 256) + ci] = f2bf(w[(co * 256 + ci) * 9 + tap]);
}

// ---------------------------------------------------------------------------
// Pass 3: 256(co) x 112(n) implicit GEMM, BK=32, K=2304 = 72 kt, TAP-INNER
// order (L2-hot: FETCH ~59MB verified R6). grid=896, block=256 (4 waves,
// each 64co x 112n). NEW vs R6: register double-buffered fragments --
// during MFMA(kt) the ds_reads for frags(kt+1) are in flight; 1 barrier +
// 1 VMW per kt. LDS 48KB dbuf; 64B rows, swizzle col ^= (row>>1)&3,
// pre-swizzled global_load_lds source. ~240 regs -> 2 waves/SIMD,
// 2 blocks/CU co-resident.
// ---------------------------------------------------------------------------

#define BAR()    __builtin_amdgcn_s_barrier()
#define LGKM0()  asm volatile("s_waitcnt lgkmcnt(0)" ::: "memory")
#define VMW(N)   asm volatile("s_waitcnt vmcnt(" #N ")" ::: "memory")
#define SCHED0() __builtin_amdgcn_sched_barrier(0)
#define PRIO(x)  __builtin_amdgcn_s_setprio(x)

// stage kt' (parity P): A 256x32 (4/wave), B 128x32 (2/wave)
#define STAGE(P, aOffE, bOffE) do {                                           \
    _Pragma("unroll") for (int a_ = 0; a_ < 4; ++a_)                          \
        __builtin_amdgcn_global_load_lds(                                     \
            (const AS1 void*)(aSrcLane + (aOffE) + a_ * 4096),                \
            (AS3 void*)(lds + (P)*16384 + (wv*4 + a_)*1024 + lane*16),        \
            16, 0, 0);                                                        \
    _Pragma("unroll") for (int b_ = 0; b_ < 2; ++b_)                          \
        __builtin_amdgcn_global_load_lds(                                     \
            (const AS1 void*)(bL[b_] + (bOffE)),                              \
            (AS3 void*)(lds + 32768 + (P)*8192 + (wv*2 + b_)*1024 + lane*16), \
            16, 0, 0);                                                        \
} while (0)

// STAGE for next kt-target, advancing tap2/cic2 (call exactly once per kt)
#define STAGE_NEXT(P) do {                                                    \
    const int kh2 = (tap2 * 11) >> 5;                                         \
    const int kw2 = tap2 - 3 * kh2;                                           \
    STAGE(P, tap2 * 65536 + cic2 * 32,                                        \
             ((kh2 - 1) * 30 + (kw2 - 1)) * 256 + cic2 * 32);                 \
    if (++tap2 == 9) { tap2 = 0; ++cic2; }                                    \
} while (0)

#define READF(SET, P) do {                                                    \
    _Pragma("unroll") for (int m_ = 0; m_ < 4; ++m_)                          \
        fa##SET[m_] = *(const bf16x8*)(lds + (P)*16384 + aRdBase + m_*1024);  \
    _Pragma("unroll") for (int f_ = 0; f_ < 7; ++f_)                          \
        fb##SET[f_] = *(const bf16x8*)(lds + 32768 + (P)*8192 + bRdBase + f_*1024);\
} while (0)

#define MFMA28(SET) do {                                                      \
    _Pragma("unroll") for (int m_ = 0; m_ < 4; ++m_)                          \
    _Pragma("unroll") for (int f_ = 0; f_ < 7; ++f_)                          \
        acc[m_][f_] = __builtin_amdgcn_mfma_f32_16x16x32_bf16(                \
            fb##SET[f_], fa##SET[m_], acc[m_][f_], 0, 0, 0);                  \
} while (0)

__global__ __launch_bounds__(256, 2) void conv_gemm_kernel(
    const unsigned short* __restrict__ xm,
    const unsigned short* __restrict__ wB,
    float* __restrict__ out) {
    __shared__ __align__(1024) char lds[49152];

    const int tid  = threadIdx.x;
    const int wv   = tid >> 6;             // 0..3: co quarter
    const int lane = tid & 63;
    const int l15  = lane & 15;
    const int n0   = blockIdx.x * 112;

    // ---- staging sources (pre-swizzled ci offset; inverse of read swizzle) ----
    const int swzE = 8 * ((lane & 3) ^ ((lane >> 3) & 3));
    const unsigned short* aSrcLane = wB + (wv * 64 + (lane >> 2)) * 256 + swzE;

    const unsigned short* bL[2];
    #pragma unroll
    for (int b_ = 0; b_ < 2; ++b_) {
        int nl = wv * 32 + b_ * 16 + (lane >> 2);
        nl = nl > 111 ? 111 : nl;          // pad rows duplicate row 111
        const int n  = n0 + nl;
        const int w_ = n % 28, h_ = (n / 28) % 28, bt = n / 784;
        bL[b_] = xm + (size_t)((bt * 30 + h_ + 1) * 30 + (w_ + 1)) * 256 + swzE;
    }

    // ---- fragment read bases (byte offsets; swizzle col ^= (row>>1)&3) ----
    const int readSwz = ((lane >> 4) ^ ((l15 >> 1) & 3)) << 4;
    const int aRdBase = wv * 4096 + l15 * 64 + readSwz;   // + P*16384 + m*1024
    const int bRdBase = l15 * 64 + readSwz;               // + 32768 + P*8192 + f*1024

    f32x4 acc[4][7];
    #pragma unroll
    for (int i = 0; i < 4; ++i)
        #pragma unroll
        for (int j = 0; j < 7; ++j) acc[i][j] = f32x4{0.f, 0.f, 0.f, 0.f};

    bf16x8 faA[4], fbA[7], faB[4], fbB[7];

    int tap2 = 0, cic2 = 0;
    // ---- prologue: kt=0 -> buf0, kt=1 -> buf1; frags(0) -> set A ----
    STAGE_NEXT(0);                 // S(0)
    STAGE_NEXT(1);                 // S(1)
    VMW(6);                        // S(0) landed (S(1) in flight)
    SCHED0();
    BAR();
    READF(A, 0);                   // frags(0)
    LGKM0();

    // steady state invariant at top of even body (kt even, regs A = frags(kt)):
    //   outstanding vmem = S(kt+1) only -> VMW(0) exact drain
    #pragma unroll 1
    for (int kt = 0; kt < 70; kt += 2) {
        // ---- even: compute kt (set A), prefetch kt+1 (set B), stage kt+2 ----
        VMW(0);
        SCHED0();
        BAR();                     // buf1(kt+1) published; buf0 reads drained chain-wide
        READF(B, 1);               // frags(kt+1) in flight
        STAGE_NEXT(0);             // S(kt+2) -> buf0
        SCHED0();
        PRIO(1); MFMA28(A); PRIO(0);
        LGKM0();                   // frags(kt+1) in regs (hidden under MFMA)
        // ---- odd: compute kt+1 (set B), prefetch kt+2 (set A), stage kt+3 ----
        VMW(0);
        SCHED0();
        BAR();
        READF(A, 0);               // frags(kt+2)
        STAGE_NEXT(1);             // S(kt+3) -> buf1
        SCHED0();
        PRIO(1); MFMA28(B); PRIO(0);
        LGKM0();
    }
    // ---- peeled kt=70,71: regs A = frags(70); S(71) in flight ----
    VMW(0);
    SCHED0();
    BAR();
    READF(B, 1);                   // frags(71)
    SCHED0();
    PRIO(1); MFMA28(A); PRIO(0);
    LGKM0();
    PRIO(1); MFMA28(B); PRIO(0);

    // ---- C-write: lane holds 4 consecutive n (rows) at one co (col) ----
    #pragma unroll
    for (int f = 0; f < 7; ++f) {
        const int n  = n0 + f * 16 + ((lane >> 4) << 2);
        const int bt = n / 784;
        const int hw = n - bt * 784;
        const int b = bt >> 4, t = bt & 15;
        float* obase = out + ((size_t)(b * 256) * 16 + t) * 784 + hw;
        #pragma unroll
        for (int m = 0; m < 4; ++m) {
            const int co = wv * 64 + m * 16 + l15;
            *(f32x4*)(obase + (size_t)co * 12544) = acc[m][f];
        }
    }
}

// ---------------------------------------------------------------------------
extern "C" void kernel_launch(void* const* d_in, const int* in_sizes, int n_in,
                              void* d_out, int out_size, void* d_ws, size_t ws_size,
                              hipStream_t stream) {
    const float* x      = (const float*)d_in[0];
    const float* alpha  = (const float*)d_in[1];
    const float* weight = (const float*)d_in[2];
    float* out = (float*)d_out;

    unsigned short* xm = (unsigned short*)d_ws;
    unsigned short* wB = (unsigned short*)((char*)d_ws + XM_BYTES);

    modulate_kernel<<<dim3(NB * NT * HP), dim3(256), 0, stream>>>(x, alpha, xm);
    repack_w_kernel<<<dim3(9 * 256), dim3(256), 0, stream>>>(weight, wB);
    conv_gemm_kernel<<<dim3(896), dim3(256), 0, stream>>>(xm, wB, out);
}